// Round 9
// baseline (96.805 us; speedup 1.0000x reference)
//
#include <hip/hip_runtime.h>
#include <hip/hip_fp16.h>

// Cubic B-spline interpolation (SplineInter), 2D, m=1024x1024, PAD=2.
//
// History:
// R2/R7: fp32 direct, no ws                    -> eval ~48-50, total ~110
// R3: counting sort                            -> FAILED (scatter write-amp)
// R4: fp32 quad repack (4.2MB)                 -> eval 45.6
// R5: 4-copy fp32 (16.9MB)                     -> FAILED (L2 thrash)
// R6: 16-copy fp32 tile, 1 line/pt (67.6MB)    -> eval 43.3
// R8: fp16 16-copy tile, 2req/32B/1line (33.8MB)-> eval ~40
// R10: fp16 quad grid 2.1MB, L2-RESIDENT       -> eval ~28, TOTAL 91.6 (WIN)
//     Confirmed: the 43-50us invariant was random-line HBM refill after the
//     unconditional 256MB poison; <4MB/XCD working set fixed it.
//     Fixed harness floor: 46 poison + ~14.5 overhead = 60.5us.
//     Eval now L1-miss/request-rate bound: 8M 16B requests (4/pt).
// R11: row-phase fp16 replication x4 (8.5MB). Copy p holds rows 4i+p..+3
//     per 8B elem, col fast axis -> a point's 16 coeffs are 32 CONTIGUOUS
//     bytes = 2 requests/pt (halves the miss path). w0 applies directly
//     (no shifted weights). 8.5MB: ~47% L2 + rest L3-resident (compulsory
//     HBM only 8.5MB). 2 pts/thread for MLP; nontemporal x/out.
//     Predict: eval 15-22, pack ~3 (WRITE 8.5MB), total 80-87.
//     Falsifier: eval >= 28 -> request count not binding; revert to R10.

#define I1 1028
#define TOTAL (1028 * 1028)
#define NI 257                      // i = r0>>2 in [0,256]
#define CPE (NI * I1)               // elems per copy = 264196
#define RELEMS (4 * CPE)            // 1,056,784 x 8B = 8.45 MB

// 4-float vector, 4-byte alignment (fallback path row loads).
typedef float f4u __attribute__((ext_vector_type(4), aligned(4)));
// Native clang vectors for nontemporal builtins.
typedef float f2v __attribute__((ext_vector_type(2)));
typedef float f4v __attribute__((ext_vector_type(4)));
// 16B load with 8B alignment guarantee (elements are 8B).
typedef unsigned int u4a8 __attribute__((ext_vector_type(4), aligned(8)));

__device__ __forceinline__ void basis4(float t, float w[4]) {
    float a = 1.0f - t;
    w[0] = a * a * a;                                // j=-1: (1-t)^3
    w[1] = (3.0f * t - 6.0f) * (t * t) + 4.0f;       // j=0
    float xi = t - 1.0f;
    w[2] = -(3.0f * xi + 6.0f) * (xi * xi) + 4.0f;   // j=1
    w[3] = t * t * t;                                // j=2
}

__device__ __forceinline__ float2 h2f(unsigned int u) {
    __half2 h = *reinterpret_cast<__half2*>(&u);
    return __half22float2(h);
}

// ---------------- fp16 row-phase pack (8.5 MB, ~3 us) ----------------
// QR[((p*NI + i)*I1 + c)] = 8B fp16 of rows 4i+p..4i+p+3 at col c.

__global__ __launch_bounds__(256) void pack_f16r_kernel(
    const float* __restrict__ coeffs, uint2* __restrict__ QR)
{
    int t = blockIdx.x * blockDim.x + threadIdx.x;
    if (t >= RELEMS) return;
    int p   = t / CPE;
    int rem = t - p * CPE;
    int i   = rem / I1;
    int c   = rem - i * I1;
    int rb  = 4 * i + p;
    // Consecutive threads share rows, read consecutive c -> coalesced.
    // Clamp protects never-read variants (only p=0 reaches i=256).
    float v0 = coeffs[min(rb + 0, 1027) * I1 + c];
    float v1 = coeffs[min(rb + 1, 1027) * I1 + c];
    float v2 = coeffs[min(rb + 2, 1027) * I1 + c];
    float v3 = coeffs[min(rb + 3, 1027) * I1 + c];
    unsigned h0 = __half_as_ushort(__float2half(v0));
    unsigned h1 = __half_as_ushort(__float2half(v1));
    unsigned h2 = __half_as_ushort(__float2half(v2));
    unsigned h3 = __half_as_ushort(__float2half(v3));
    uint2 e;
    e.x = h0 | (h1 << 16);   // rows rb, rb+1
    e.y = h2 | (h3 << 16);   // rows rb+2, rb+3
    QR[t] = e;
}

// ---------------- Eval: 2 requests/point ----------------

struct PtOut { float v; bool valid; };

__device__ __forceinline__ PtOut eval_point(
    float px, float py,
    const ushort* __restrict__ QR,
    const float* __restrict__ coeffs)
{
    PtOut r;
    float xn0 = px * 1024.0f - 0.5f;
    float xn1 = py * 1024.0f - 0.5f;

    r.valid = (xn0 > -2.0f) && (xn0 < 1024.0f) &&
              (xn1 > -2.0f) && (xn1 < 1024.0f);

    float P0f = floorf(xn0);
    float P1f = floorf(xn1);
    int P0 = (int)P0f;
    int P1 = (int)P1f;
    float t0 = xn0 - P0f;
    float t1 = xn1 - P1f;

    int r0 = P0 + 1;   // [0,1024] for all in-range inputs
    int c0 = P1 + 1;
    bool interior = (r0 >= 0) && (r0 <= 1024) && (c0 >= 0) && (c0 <= 1024);

    if (interior) {
        int p = r0 & 3;
        int i = r0 >> 2;
        // Element index; 32 contiguous bytes cover cols c0..c0+3.
        size_t e = ((size_t)(p * NI + i) * I1 + c0);
        const ushort* base = QR + e * 4;
        u4a8 A = *reinterpret_cast<const u4a8*>(base);      // cols c0, c0+1
        u4a8 B = *reinterpret_cast<const u4a8*>(base + 8);  // cols c0+2, c0+3

        float w0[4], w1[4];
        basis4(t0, w0);   // row weights — apply DIRECTLY (rows are exact)
        basis4(t1, w1);   // col weights

        float2 a, b;
        a = h2f(A.x); b = h2f(A.y);   // col c0: rows 01, rows 23
        float cs0 = fmaf(a.x, w0[0], fmaf(a.y, w0[1],
                    fmaf(b.x, w0[2], b.y * w0[3])));
        a = h2f(A.z); b = h2f(A.w);   // col c0+1
        float cs1 = fmaf(a.x, w0[0], fmaf(a.y, w0[1],
                    fmaf(b.x, w0[2], b.y * w0[3])));
        a = h2f(B.x); b = h2f(B.y);   // col c0+2
        float cs2 = fmaf(a.x, w0[0], fmaf(a.y, w0[1],
                    fmaf(b.x, w0[2], b.y * w0[3])));
        a = h2f(B.z); b = h2f(B.w);   // col c0+3
        float cs3 = fmaf(a.x, w0[0], fmaf(a.y, w0[1],
                    fmaf(b.x, w0[2], b.y * w0[3])));

        r.v = fmaf(cs0, w1[0], fmaf(cs1, w1[1],
              fmaf(cs2, w1[2], cs3 * w1[3])));
    } else {
        // Safety path: exact fp32 flat-clamped gather (matches jnp.clip).
        float w0[4], w1[4];
        basis4(t0, w0);
        basis4(t1, w1);
        int base = I1 * (2 + P0) + (2 + P1);
        float acc = 0.0f;
#pragma unroll
        for (int j = 0; j < 4; ++j) {
            int rr = base + (j - 1) * I1 - 1;
            float s = 0.0f;
#pragma unroll
            for (int k = 0; k < 4; ++k) {
                int idx = rr + k;
                idx = min(max(idx, 0), TOTAL - 1);
                s = fmaf(coeffs[idx], w1[k], s);
            }
            acc = fmaf(s, w0[j], acc);
        }
        r.v = acc;
    }
    return r;
}

__global__ __launch_bounds__(256) void eval_f16r_kernel(
    const float* __restrict__ x,       // [N,2] interleaved
    const float* __restrict__ coeffs,  // original fp32 (safety path)
    const ushort* __restrict__ QR,     // fp16 row-phase grid (8.5 MB)
    float* __restrict__ out, int n)
{
    int g = blockIdx.x * blockDim.x + threadIdx.x;
    int i0 = 2 * g;
    if (i0 >= n) return;

    if (i0 + 1 < n) {
        // Two consecutive points: one nontemporal 16B x-load, 4 gather
        // requests in flight, one nontemporal 8B out-store.
        f4v two = __builtin_nontemporal_load(reinterpret_cast<const f4v*>(x) + g);
        PtOut a = eval_point(two.x, two.y, QR, coeffs);
        PtOut b = eval_point(two.z, two.w, QR, coeffs);
        f2v o;
        o.x = a.valid ? a.v : 0.0f;
        o.y = b.valid ? b.v : 0.0f;
        __builtin_nontemporal_store(o, reinterpret_cast<f2v*>(out) + g);
    } else {
        float px = x[2 * i0], py = x[2 * i0 + 1];
        PtOut a = eval_point(px, py, QR, coeffs);
        out[i0] = a.valid ? a.v : 0.0f;
    }
}

// ---------------- Fallback direct kernel (R7, proven) ----------------

__global__ __launch_bounds__(256) void spline_1pt_kernel(
    const float* __restrict__ x,
    const float* __restrict__ coeffs,
    float* __restrict__ out, int n)
{
    int i = blockIdx.x * blockDim.x + threadIdx.x;
    if (i >= n) return;

    float2 xy = reinterpret_cast<const float2*>(x)[i];
    float xn0 = xy.x * 1024.0f - 0.5f;
    float xn1 = xy.y * 1024.0f - 0.5f;

    bool valid = (xn0 > -2.0f) && (xn0 < 1024.0f) &&
                 (xn1 > -2.0f) && (xn1 < 1024.0f);

    float P0f = floorf(xn0);
    float P1f = floorf(xn1);
    int P0 = (int)P0f;
    int P1 = (int)P1f;
    float t0 = xn0 - P0f;
    float t1 = xn1 - P1f;

    int base = I1 * (2 + P0) + (2 + P1);
    int r0 = P0 + 1;
    int c0 = P1 + 1;
    bool interior = (r0 >= 0) && (r0 <= 1024) && (c0 >= 0) && (c0 <= 1024);

    float acc;
    if (interior) {
        const float* rowp = coeffs + base - I1 - 1;
        f4u v0 = *reinterpret_cast<const f4u*>(rowp);
        f4u v1 = *reinterpret_cast<const f4u*>(rowp + I1);
        f4u v2 = *reinterpret_cast<const f4u*>(rowp + 2 * I1);
        f4u v3 = *reinterpret_cast<const f4u*>(rowp + 3 * I1);

        float w0[4], w1[4];
        basis4(t0, w0);
        basis4(t1, w1);

        float s0 = fmaf(v0.x, w1[0], fmaf(v0.y, w1[1], fmaf(v0.z, w1[2], v0.w * w1[3])));
        float s1 = fmaf(v1.x, w1[0], fmaf(v1.y, w1[1], fmaf(v1.z, w1[2], v1.w * w1[3])));
        float s2 = fmaf(v2.x, w1[0], fmaf(v2.y, w1[1], fmaf(v2.z, w1[2], v2.w * w1[3])));
        float s3 = fmaf(v3.x, w1[0], fmaf(v3.y, w1[1], fmaf(v3.z, w1[2], v3.w * w1[3])));

        acc = fmaf(s0, w0[0], fmaf(s1, w0[1], fmaf(s2, w0[2], s3 * w0[3])));
    } else {
        float w0[4], w1[4];
        basis4(t0, w0);
        basis4(t1, w1);
        acc = 0.0f;
#pragma unroll
        for (int j = 0; j < 4; ++j) {
            int r = base + (j - 1) * I1 - 1;
            float s = 0.0f;
#pragma unroll
            for (int k = 0; k < 4; ++k) {
                int idx = r + k;
                idx = min(max(idx, 0), TOTAL - 1);
                s = fmaf(coeffs[idx], w1[k], s);
            }
            acc = fmaf(s, w0[j], acc);
        }
    }

    out[i] = valid ? acc : 0.0f;
}

// ---------------- Launch ----------------

extern "C" void kernel_launch(void* const* d_in, const int* in_sizes, int n_in,
                              void* d_out, int out_size, void* d_ws, size_t ws_size,
                              hipStream_t stream) {
    const float* x = (const float*)d_in[0];       // [N,2]
    const float* coeffs = (const float*)d_in[1];  // [1028*1028]
    float* out = (float*)d_out;                   // [N]

    int n = in_sizes[0] / 2;   // number of points (2,097,152)

    size_t need = (size_t)RELEMS * 8;   // 8.45 MB row-phase fp16 grid

    if (ws_size >= need) {
        uint2* QR = (uint2*)d_ws;

        int gpack = (RELEMS + 255) / 256;
        pack_f16r_kernel<<<gpack, 256, 0, stream>>>(coeffs, QR);

        int pairs = (n + 1) / 2;
        int geval = (pairs + 255) / 256;
        eval_f16r_kernel<<<geval, 256, 0, stream>>>(
            x, coeffs, (const ushort*)d_ws, out, n);
    } else {
        int block = 256;
        int grid = (n + block - 1) / block;
        spline_1pt_kernel<<<grid, block, 0, stream>>>(x, coeffs, out, n);
    }
}

// Round 10
// 93.520 us; speedup vs baseline: 1.0351x; 1.0351x over previous
//
#include <hip/hip_runtime.h>
#include <hip/hip_fp16.h>

// Cubic B-spline interpolation (SplineInter), 2D, m=1024x1024, PAD=2.
//
// History:
// R2/R7: fp32 direct, no ws                    -> eval ~48-50, total ~110
// R3: counting sort                            -> FAILED (scatter write-amp)
// R4: fp32 quad repack (4.2MB)                 -> eval 45.6
// R5: 4-copy fp32 (16.9MB)                     -> FAILED (L2 thrash)
// R6: 16-copy fp32 tile, 1 line/pt (67.6MB)    -> eval 43.3
// R8: fp16 16-copy tile (33.8MB)               -> eval ~40
// R10: fp16 quad grid 2.1MB, L2-RESIDENT       -> eval ~28, TOTAL 91.6 (BEST)
// R11: fp16 row-phase x4 (8.5MB, 2 req/pt)     -> eval ~33, total 96.8. LAW:
//     L2-residency >> request count. 2req/pt needs >=4x replication > 4MB
//     L2; fp8 fits but fails tolerance (6% rel x 36 weight-sum). R10's
//     layout is the optimum. Budget: 46 poison + ~15 overhead (fixed) +
//     2 pack + 28 eval. Request floor ~13us; 2x gap = latency tails at
//     only 4 outstanding req/thread (1pt/thread).
// R12: R10 + 2 pts/thread: 8 outstanding gathers, nontemporal float4 x /
//     float2 out (halves streaming instr count). Predict eval 20-24,
//     total 84-88. Falsifier: eval ~28 -> TA-serialization floor reached;
//     declare harness-dominated roofline (~89).

#define I1 1028
#define TOTAL (1028 * 1028)
#define NQ 258                     // quad-row groups 0..257 (pad group so
                                   // qi+1 is always in-bounds)
#define QELEMS (NQ * I1)           // 265224 x 8B = 2.12 MB

// 4-float vector, 4-byte alignment (fallback path row loads).
typedef float f4u __attribute__((ext_vector_type(4), aligned(4)));
// Native clang vectors for nontemporal builtins.
typedef float f2v __attribute__((ext_vector_type(2)));
typedef float f4v __attribute__((ext_vector_type(4)));
// 16B load with 8B alignment guarantee (QH elements are 8B).
typedef unsigned int u4a8 __attribute__((ext_vector_type(4), aligned(8)));

__device__ __forceinline__ void basis4(float t, float w[4]) {
    float a = 1.0f - t;
    w[0] = a * a * a;                                // j=-1: (1-t)^3
    w[1] = (3.0f * t - 6.0f) * (t * t) + 4.0f;       // j=0
    float xi = t - 1.0f;
    w[2] = -(3.0f * xi + 6.0f) * (xi * xi) + 4.0f;   // j=1
    w[3] = t * t * t;                                // j=2
}

__device__ __forceinline__ float2 h2f(unsigned int u) {
    __half2 h = *reinterpret_cast<__half2*>(&u);
    return __half22float2(h);
}

// W[t] = w0[t-s] for t-s in [0,4), else 0. Proven in R4/R10.
__device__ __forceinline__ void shifted_w8(const float w0[4], int s, float W[8]) {
#pragma unroll
    for (int t = 0; t < 8; ++t) {
        float v = 0.0f;
        if (t - 0 >= 0 && t - 0 < 4) v = (s == 0) ? w0[t - 0] : v;
        if (t - 1 >= 0 && t - 1 < 4) v = (s == 1) ? w0[t - 1] : v;
        if (t - 2 >= 0 && t - 2 < 4) v = (s == 2) ? w0[t - 2] : v;
        if (t - 3 >= 0 && t - 3 < 4) v = (s == 3) ? w0[t - 3] : v;
        W[t] = v;
    }
}

// One column: 8 window rows (4 from quad qi, 4 from quad qi+1).
__device__ __forceinline__ float col8(unsigned a01, unsigned a23,
                                      unsigned b01, unsigned b23,
                                      const float W[8]) {
    float2 p0 = h2f(a01);
    float2 p1 = h2f(a23);
    float2 p2 = h2f(b01);
    float2 p3 = h2f(b23);
    return fmaf(p0.x, W[0], fmaf(p0.y, W[1],
           fmaf(p1.x, W[2], fmaf(p1.y, W[3],
           fmaf(p2.x, W[4], fmaf(p2.y, W[5],
           fmaf(p3.x, W[6], p3.y * W[7])))))));
}

// ---------------- fp16 quad-row pack (2.1 MB, ~2 us) ----------------

__global__ __launch_bounds__(256) void pack_f16q_kernel(
    const float* __restrict__ coeffs, uint2* __restrict__ QH)
{
    int t = blockIdx.x * blockDim.x + threadIdx.x;
    if (t >= QELEMS) return;
    int qi = t / I1;
    int c  = t - qi * I1;
    int rb = 4 * qi;
    float v0 = coeffs[min(rb + 0, 1027) * I1 + c];
    float v1 = coeffs[min(rb + 1, 1027) * I1 + c];
    float v2 = coeffs[min(rb + 2, 1027) * I1 + c];
    float v3 = coeffs[min(rb + 3, 1027) * I1 + c];
    unsigned h0 = __half_as_ushort(__float2half(v0));
    unsigned h1 = __half_as_ushort(__float2half(v1));
    unsigned h2 = __half_as_ushort(__float2half(v2));
    unsigned h3 = __half_as_ushort(__float2half(v3));
    uint2 e;
    e.x = h0 | (h1 << 16);
    e.y = h2 | (h3 << 16);
    QH[t] = e;
}

// ---------------- Eval: 2 points per thread, 8 outstanding gathers -------

struct Setup {
    const ushort* base;   // gather base (interior) — issued first
    float t0, t1;
    int s;
    bool valid, interior;
    int P0, P1;
};

__device__ __forceinline__ Setup setup_pt(float px, float py,
                                          const ushort* __restrict__ QH) {
    Setup sp;
    float xn0 = px * 1024.0f - 0.5f;
    float xn1 = py * 1024.0f - 0.5f;
    sp.valid = (xn0 > -2.0f) && (xn0 < 1024.0f) &&
               (xn1 > -2.0f) && (xn1 < 1024.0f);
    float P0f = floorf(xn0);
    float P1f = floorf(xn1);
    sp.P0 = (int)P0f;
    sp.P1 = (int)P1f;
    sp.t0 = xn0 - P0f;
    sp.t1 = xn1 - P1f;
    int r0 = sp.P0 + 1;
    int c0 = sp.P1 + 1;
    sp.interior = (r0 >= 0) && (r0 <= 1024) && (c0 >= 0) && (c0 <= 1024);
    sp.s = r0 & 3;
    int qi = r0 >> 2;
    int cc = sp.interior ? c0 : 0;      // safe dummy when exterior
    int qq = sp.interior ? qi : 0;
    sp.base = QH + (size_t)(qq * I1 + cc) * 4;
    return sp;
}

__device__ __forceinline__ float finish_pt(const Setup& sp,
                                           u4a8 A0, u4a8 A1, u4a8 B0, u4a8 B1,
                                           const float* __restrict__ coeffs) {
    if (sp.interior) {
        float w0[4], w1[4];
        basis4(sp.t0, w0);
        basis4(sp.t1, w1);
        float W[8];
        shifted_w8(w0, sp.s, W);
        float cs0 = col8(A0.x, A0.y, B0.x, B0.y, W);
        float cs1 = col8(A0.z, A0.w, B0.z, B0.w, W);
        float cs2 = col8(A1.x, A1.y, B1.x, B1.y, W);
        float cs3 = col8(A1.z, A1.w, B1.z, B1.w, W);
        return fmaf(cs0, w1[0], fmaf(cs1, w1[1],
               fmaf(cs2, w1[2], cs3 * w1[3])));
    }
    // Safety path: exact fp32 flat-clamped gather (matches jnp.clip).
    float w0[4], w1[4];
    basis4(sp.t0, w0);
    basis4(sp.t1, w1);
    int base = I1 * (2 + sp.P0) + (2 + sp.P1);
    float acc = 0.0f;
#pragma unroll
    for (int j = 0; j < 4; ++j) {
        int rr = base + (j - 1) * I1 - 1;
        float s = 0.0f;
#pragma unroll
        for (int k = 0; k < 4; ++k) {
            int idx = rr + k;
            idx = min(max(idx, 0), TOTAL - 1);
            s = fmaf(coeffs[idx], w1[k], s);
        }
        acc = fmaf(s, w0[j], acc);
    }
    return acc;
}

__global__ __launch_bounds__(256) void eval_f16q2_kernel(
    const float* __restrict__ x,       // [N,2] interleaved
    const float* __restrict__ coeffs,  // original fp32 (safety path)
    const ushort* __restrict__ QH,     // fp16 quad grid (2.1 MB)
    float* __restrict__ out, int n)
{
    int g = blockIdx.x * blockDim.x + threadIdx.x;
    int i0 = 2 * g;
    if (i0 >= n) return;

    if (i0 + 1 < n) {
        // One nontemporal 16B x-load for both points.
        f4v two = __builtin_nontemporal_load(reinterpret_cast<const f4v*>(x) + g);
        Setup sa = setup_pt(two.x, two.y, QH);
        Setup sb = setup_pt(two.z, two.w, QH);

        // Issue ALL EIGHT gather requests back-to-back (2 pts x 2 quad-rows
        // x 2 x 16B) before any weight math -> 8 outstanding per thread.
        const ushort* pa0 = sa.base;
        const ushort* pa1 = sa.base + (size_t)I1 * 4;
        const ushort* pb0 = sb.base;
        const ushort* pb1 = sb.base + (size_t)I1 * 4;
        u4a8 aA0 = *reinterpret_cast<const u4a8*>(pa0);
        u4a8 aA1 = *reinterpret_cast<const u4a8*>(pa0 + 8);
        u4a8 aB0 = *reinterpret_cast<const u4a8*>(pa1);
        u4a8 aB1 = *reinterpret_cast<const u4a8*>(pa1 + 8);
        u4a8 bA0 = *reinterpret_cast<const u4a8*>(pb0);
        u4a8 bA1 = *reinterpret_cast<const u4a8*>(pb0 + 8);
        u4a8 bB0 = *reinterpret_cast<const u4a8*>(pb1);
        u4a8 bB1 = *reinterpret_cast<const u4a8*>(pb1 + 8);

        float va = finish_pt(sa, aA0, aA1, aB0, aB1, coeffs);
        float vb = finish_pt(sb, bA0, bA1, bB0, bB1, coeffs);

        f2v o;
        o.x = sa.valid ? va : 0.0f;
        o.y = sb.valid ? vb : 0.0f;
        __builtin_nontemporal_store(o, reinterpret_cast<f2v*>(out) + g);
    } else {
        float px = x[2 * i0], py = x[2 * i0 + 1];
        Setup sa = setup_pt(px, py, QH);
        const ushort* pa0 = sa.base;
        const ushort* pa1 = sa.base + (size_t)I1 * 4;
        u4a8 A0 = *reinterpret_cast<const u4a8*>(pa0);
        u4a8 A1 = *reinterpret_cast<const u4a8*>(pa0 + 8);
        u4a8 B0 = *reinterpret_cast<const u4a8*>(pa1);
        u4a8 B1 = *reinterpret_cast<const u4a8*>(pa1 + 8);
        float va = finish_pt(sa, A0, A1, B0, B1, coeffs);
        out[i0] = sa.valid ? va : 0.0f;
    }
}

// ---------------- Fallback direct kernel (R7, proven) ----------------

__global__ __launch_bounds__(256) void spline_1pt_kernel(
    const float* __restrict__ x,
    const float* __restrict__ coeffs,
    float* __restrict__ out, int n)
{
    int i = blockIdx.x * blockDim.x + threadIdx.x;
    if (i >= n) return;

    float2 xy = reinterpret_cast<const float2*>(x)[i];
    float xn0 = xy.x * 1024.0f - 0.5f;
    float xn1 = xy.y * 1024.0f - 0.5f;

    bool valid = (xn0 > -2.0f) && (xn0 < 1024.0f) &&
                 (xn1 > -2.0f) && (xn1 < 1024.0f);

    float P0f = floorf(xn0);
    float P1f = floorf(xn1);
    int P0 = (int)P0f;
    int P1 = (int)P1f;
    float t0 = xn0 - P0f;
    float t1 = xn1 - P1f;

    int base = I1 * (2 + P0) + (2 + P1);
    int r0 = P0 + 1;
    int c0 = P1 + 1;
    bool interior = (r0 >= 0) && (r0 <= 1024) && (c0 >= 0) && (c0 <= 1024);

    float acc;
    if (interior) {
        const float* rowp = coeffs + base - I1 - 1;
        f4u v0 = *reinterpret_cast<const f4u*>(rowp);
        f4u v1 = *reinterpret_cast<const f4u*>(rowp + I1);
        f4u v2 = *reinterpret_cast<const f4u*>(rowp + 2 * I1);
        f4u v3 = *reinterpret_cast<const f4u*>(rowp + 3 * I1);

        float w0[4], w1[4];
        basis4(t0, w0);
        basis4(t1, w1);

        float s0 = fmaf(v0.x, w1[0], fmaf(v0.y, w1[1], fmaf(v0.z, w1[2], v0.w * w1[3])));
        float s1 = fmaf(v1.x, w1[0], fmaf(v1.y, w1[1], fmaf(v1.z, w1[2], v1.w * w1[3])));
        float s2 = fmaf(v2.x, w1[0], fmaf(v2.y, w1[1], fmaf(v2.z, w1[2], v2.w * w1[3])));
        float s3 = fmaf(v3.x, w1[0], fmaf(v3.y, w1[1], fmaf(v3.z, w1[2], v3.w * w1[3])));

        acc = fmaf(s0, w0[0], fmaf(s1, w0[1], fmaf(s2, w0[2], s3 * w0[3])));
    } else {
        float w0[4], w1[4];
        basis4(t0, w0);
        basis4(t1, w1);
        acc = 0.0f;
#pragma unroll
        for (int j = 0; j < 4; ++j) {
            int r = base + (j - 1) * I1 - 1;
            float s = 0.0f;
#pragma unroll
            for (int k = 0; k < 4; ++k) {
                int idx = r + k;
                idx = min(max(idx, 0), TOTAL - 1);
                s = fmaf(coeffs[idx], w1[k], s);
            }
            acc = fmaf(s, w0[j], acc);
        }
    }

    out[i] = valid ? acc : 0.0f;
}

// ---------------- Launch ----------------

extern "C" void kernel_launch(void* const* d_in, const int* in_sizes, int n_in,
                              void* d_out, int out_size, void* d_ws, size_t ws_size,
                              hipStream_t stream) {
    const float* x = (const float*)d_in[0];       // [N,2]
    const float* coeffs = (const float*)d_in[1];  // [1028*1028]
    float* out = (float*)d_out;                   // [N]

    int n = in_sizes[0] / 2;   // number of points (2,097,152)

    size_t need = (size_t)QELEMS * 8;   // 2.12 MB fp16 quad grid

    if (ws_size >= need) {
        uint2* QH = (uint2*)d_ws;

        int gpack = (QELEMS + 255) / 256;
        pack_f16q_kernel<<<gpack, 256, 0, stream>>>(coeffs, QH);

        int pairs = (n + 1) / 2;
        int geval = (pairs + 255) / 256;
        eval_f16q2_kernel<<<geval, 256, 0, stream>>>(
            x, coeffs, (const ushort*)d_ws, out, n);
    } else {
        int block = 256;
        int grid = (n + block - 1) / block;
        spline_1pt_kernel<<<grid, block, 0, stream>>>(x, coeffs, out, n);
    }
}

// Round 11
// 92.714 us; speedup vs baseline: 1.0441x; 1.0087x over previous
//
#include <hip/hip_runtime.h>
#include <hip/hip_fp16.h>

// Cubic B-spline interpolation (SplineInter), 2D, m=1024x1024, PAD=2.
//
// FINAL KERNEL (R10 revert, best verified: 91.6 us total).
//
// Session findings (SplineInter on MI355X, N=2M random points, grid 1028^2):
// - Harness poisons the FULL 256 MB workspace with fillBufferAligned
//   (~46 us) EVERY timed iteration, UNCONDITIONALLY (even when d_ws is
//   unused, R7). This also wipes L2/L3. Fixed tax: ~46 + ~15 us overhead.
// - Consequence: any gather working set >= per-XCD L2 (4 MB) re-fills from
//   HBM at random-64B-line BW (~1.1-1.7 TB/s) -> invariant ~43-50 us eval
//   regardless of layout geometry (R2/R4/R6/R8: lines/pt 1..4.75, req/pt
//   2..8 all identical). L2-RESIDENCY DOMINATES EVERYTHING.
// - fp16 quad-row grid = 2.12 MB < 4 MB/XCD -> L2-resident -> eval ~28 us
//   (R10). fp16 passes tolerance (absmax 0.03125 = threshold; fp16 err
//   ~3e-3). fp8 would fail (6% rel x 36-weight sum).
// - Remaining eval cost is the TA/request floor: 4 uncoalesced 16B
//   lane-requests/pt (minimum for 64 B/pt) at ~2.1 cyc/req ~ 27 us.
//   Closed escape routes: 2 req/pt needs 4x replication -> L2 thrash
//   (R11, +5us); sort for coalescing -> scatter write-amp (R3, +160us);
//   more MLP -> null (R12); fp8 -> tolerance.
// - Composed floor: 46 + 15 + 2 (pack) + 28 (eval) ~ 91 us. R10 = 91.6.

#define I1 1028
#define TOTAL (1028 * 1028)
#define NQ 258                     // quad-row groups 0..257 (one pad group so
                                   // the qi+1 load is always in-bounds)
#define QELEMS (NQ * I1)           // 265224 x 8B = 2.12 MB

// 4-float vector, 4-byte alignment (fallback path row loads).
typedef float f4u __attribute__((ext_vector_type(4), aligned(4)));
// Native clang vector types (required by __builtin_nontemporal_*).
typedef float f2v __attribute__((ext_vector_type(2)));
// 16B load with only 8B alignment guarantee (QH elements are 8B).
typedef unsigned int u4a8 __attribute__((ext_vector_type(4), aligned(8)));

__device__ __forceinline__ void basis4(float t, float w[4]) {
    float a = 1.0f - t;
    w[0] = a * a * a;                                // j=-1: (1-t)^3
    w[1] = (3.0f * t - 6.0f) * (t * t) + 4.0f;       // j=0
    float xi = t - 1.0f;
    w[2] = -(3.0f * xi + 6.0f) * (xi * xi) + 4.0f;   // j=1
    w[3] = t * t * t;                                // j=2
}

__device__ __forceinline__ float2 h2f(unsigned int u) {
    __half2 h = *reinterpret_cast<__half2*>(&u);
    return __half22float2(h);
}

// W[t] = w0[t-s] for t-s in [0,4), else 0.
__device__ __forceinline__ void shifted_w8(const float w0[4], int s, float W[8]) {
#pragma unroll
    for (int t = 0; t < 8; ++t) {
        float v = 0.0f;
        if (t - 0 >= 0 && t - 0 < 4) v = (s == 0) ? w0[t - 0] : v;
        if (t - 1 >= 0 && t - 1 < 4) v = (s == 1) ? w0[t - 1] : v;
        if (t - 2 >= 0 && t - 2 < 4) v = (s == 2) ? w0[t - 2] : v;
        if (t - 3 >= 0 && t - 3 < 4) v = (s == 3) ? w0[t - 3] : v;
        W[t] = v;
    }
}

// One column: 8 stencil-window rows (4 from quad qi, 4 from quad qi+1).
__device__ __forceinline__ float col8(unsigned a01, unsigned a23,
                                      unsigned b01, unsigned b23,
                                      const float W[8]) {
    float2 p0 = h2f(a01);   // rows 4qi+0, 4qi+1
    float2 p1 = h2f(a23);   // rows 4qi+2, 4qi+3
    float2 p2 = h2f(b01);   // rows 4qi+4, 4qi+5
    float2 p3 = h2f(b23);   // rows 4qi+6, 4qi+7
    return fmaf(p0.x, W[0], fmaf(p0.y, W[1],
           fmaf(p1.x, W[2], fmaf(p1.y, W[3],
           fmaf(p2.x, W[4], fmaf(p2.y, W[5],
           fmaf(p3.x, W[6], p3.y * W[7])))))));
}

// ---------------- fp16 quad-row pack (~2.1 MB, ~2 us) ----------------
// QH[qi*I1 + c] = 8B = fp16 of rows 4qi..4qi+3 (clamped) at col c.

__global__ __launch_bounds__(256) void pack_f16q_kernel(
    const float* __restrict__ coeffs, uint2* __restrict__ QH)
{
    int t = blockIdx.x * blockDim.x + threadIdx.x;
    if (t >= QELEMS) return;
    int qi = t / I1;
    int c  = t - qi * I1;
    int rb = 4 * qi;
    // Coalesced: consecutive threads read consecutive c within the same rows.
    float v0 = coeffs[min(rb + 0, 1027) * I1 + c];
    float v1 = coeffs[min(rb + 1, 1027) * I1 + c];
    float v2 = coeffs[min(rb + 2, 1027) * I1 + c];
    float v3 = coeffs[min(rb + 3, 1027) * I1 + c];
    unsigned h0 = __half_as_ushort(__float2half(v0));
    unsigned h1 = __half_as_ushort(__float2half(v1));
    unsigned h2 = __half_as_ushort(__float2half(v2));
    unsigned h3 = __half_as_ushort(__float2half(v3));
    uint2 e;
    e.x = h0 | (h1 << 16);
    e.y = h2 | (h3 << 16);
    QH[t] = e;
}

// ---------------- Eval on L2-resident fp16 quad grid ----------------

__global__ __launch_bounds__(256) void eval_f16q_kernel(
    const float* __restrict__ x,       // [N,2] interleaved
    const float* __restrict__ coeffs,  // original fp32 (safety path)
    const ushort* __restrict__ QH,     // fp16 quad-row grid (2.1 MB)
    float* __restrict__ out, int n)
{
    int i = blockIdx.x * blockDim.x + threadIdx.x;
    if (i >= n) return;

    // Non-temporal: keep the streaming x out of L2 so QH stays resident.
    f2v xy = __builtin_nontemporal_load(reinterpret_cast<const f2v*>(x) + i);

    float xn0 = xy.x * 1024.0f - 0.5f;
    float xn1 = xy.y * 1024.0f - 0.5f;

    bool valid = (xn0 > -2.0f) && (xn0 < 1024.0f) &&
                 (xn1 > -2.0f) && (xn1 < 1024.0f);

    float P0f = floorf(xn0);
    float P1f = floorf(xn1);
    int P0 = (int)P0f;
    int P1 = (int)P1f;
    float t0 = xn0 - P0f;
    float t1 = xn1 - P1f;

    int r0 = P0 + 1;   // first stencil row, padded coords (in [0,1024])
    int c0 = P1 + 1;   // first stencil col
    bool interior = (r0 >= 0) && (r0 <= 1024) && (c0 >= 0) && (c0 <= 1024);

    float acc;
    if (interior) {
        int s  = r0 & 3;
        int qi = r0 >> 2;        // <= 256; qi+1 <= 257 covered by pad group
        // Issue all 4 loads first: 2 quad-rows x 4 cols = 2 x 32B regions.
        const ushort* pA = QH + (size_t)(qi * I1 + c0) * 4;
        const ushort* pB = pA + (size_t)I1 * 4;
        u4a8 A0 = *reinterpret_cast<const u4a8*>(pA);       // cols c0, c0+1
        u4a8 A1 = *reinterpret_cast<const u4a8*>(pA + 8);   // cols c0+2, c0+3
        u4a8 B0 = *reinterpret_cast<const u4a8*>(pB);
        u4a8 B1 = *reinterpret_cast<const u4a8*>(pB + 8);

        float w0[4], w1[4];
        basis4(t0, w0);   // row weights
        basis4(t1, w1);   // col weights
        float W[8];
        shifted_w8(w0, s, W);

        float cs0 = col8(A0.x, A0.y, B0.x, B0.y, W);
        float cs1 = col8(A0.z, A0.w, B0.z, B0.w, W);
        float cs2 = col8(A1.x, A1.y, B1.x, B1.y, W);
        float cs3 = col8(A1.z, A1.w, B1.z, B1.w, W);

        acc = fmaf(cs0, w1[0], fmaf(cs1, w1[1],
              fmaf(cs2, w1[2], cs3 * w1[3])));
    } else {
        // Safety path (NaN / out-of-range): exact fp32 flat-clamped gather.
        float w0[4], w1[4];
        basis4(t0, w0);
        basis4(t1, w1);
        int base = I1 * (2 + P0) + (2 + P1);
        acc = 0.0f;
#pragma unroll
        for (int j = 0; j < 4; ++j) {
            int r = base + (j - 1) * I1 - 1;
            float sum = 0.0f;
#pragma unroll
            for (int k = 0; k < 4; ++k) {
                int idx = r + k;
                idx = min(max(idx, 0), TOTAL - 1);
                sum = fmaf(coeffs[idx], w1[k], sum);
            }
            acc = fmaf(sum, w0[j], acc);
        }
    }

    float result = valid ? acc : 0.0f;
    __builtin_nontemporal_store(result, &out[i]);
}

// ---------------- Fallback direct kernel (R7, proven) ----------------

__global__ __launch_bounds__(256) void spline_1pt_kernel(
    const float* __restrict__ x,
    const float* __restrict__ coeffs,
    float* __restrict__ out, int n)
{
    int i = blockIdx.x * blockDim.x + threadIdx.x;
    if (i >= n) return;

    float2 xy = reinterpret_cast<const float2*>(x)[i];
    float xn0 = xy.x * 1024.0f - 0.5f;
    float xn1 = xy.y * 1024.0f - 0.5f;

    bool valid = (xn0 > -2.0f) && (xn0 < 1024.0f) &&
                 (xn1 > -2.0f) && (xn1 < 1024.0f);

    float P0f = floorf(xn0);
    float P1f = floorf(xn1);
    int P0 = (int)P0f;
    int P1 = (int)P1f;
    float t0 = xn0 - P0f;
    float t1 = xn1 - P1f;

    int base = I1 * (2 + P0) + (2 + P1);
    int r0 = P0 + 1;
    int c0 = P1 + 1;
    bool interior = (r0 >= 0) && (r0 <= 1024) && (c0 >= 0) && (c0 <= 1024);

    float acc;
    if (interior) {
        const float* rowp = coeffs + base - I1 - 1;
        f4u v0 = *reinterpret_cast<const f4u*>(rowp);
        f4u v1 = *reinterpret_cast<const f4u*>(rowp + I1);
        f4u v2 = *reinterpret_cast<const f4u*>(rowp + 2 * I1);
        f4u v3 = *reinterpret_cast<const f4u*>(rowp + 3 * I1);

        float w0[4], w1[4];
        basis4(t0, w0);
        basis4(t1, w1);

        float s0 = fmaf(v0.x, w1[0], fmaf(v0.y, w1[1], fmaf(v0.z, w1[2], v0.w * w1[3])));
        float s1 = fmaf(v1.x, w1[0], fmaf(v1.y, w1[1], fmaf(v1.z, w1[2], v1.w * w1[3])));
        float s2 = fmaf(v2.x, w1[0], fmaf(v2.y, w1[1], fmaf(v2.z, w1[2], v2.w * w1[3])));
        float s3 = fmaf(v3.x, w1[0], fmaf(v3.y, w1[1], fmaf(v3.z, w1[2], v3.w * w1[3])));

        acc = fmaf(s0, w0[0], fmaf(s1, w0[1], fmaf(s2, w0[2], s3 * w0[3])));
    } else {
        float w0[4], w1[4];
        basis4(t0, w0);
        basis4(t1, w1);
        acc = 0.0f;
#pragma unroll
        for (int j = 0; j < 4; ++j) {
            int r = base + (j - 1) * I1 - 1;
            float s = 0.0f;
#pragma unroll
            for (int k = 0; k < 4; ++k) {
                int idx = r + k;
                idx = min(max(idx, 0), TOTAL - 1);
                s = fmaf(coeffs[idx], w1[k], s);
            }
            acc = fmaf(s, w0[j], acc);
        }
    }

    out[i] = valid ? acc : 0.0f;
}

// ---------------- Launch ----------------

extern "C" void kernel_launch(void* const* d_in, const int* in_sizes, int n_in,
                              void* d_out, int out_size, void* d_ws, size_t ws_size,
                              hipStream_t stream) {
    const float* x = (const float*)d_in[0];       // [N,2]
    const float* coeffs = (const float*)d_in[1];  // [1028*1028]
    float* out = (float*)d_out;                   // [N]

    int n = in_sizes[0] / 2;   // number of points (2,097,152)

    size_t need = (size_t)QELEMS * 8;   // 2.12 MB fp16 quad grid

    if (ws_size >= need) {
        uint2* QH = (uint2*)d_ws;

        int gpack = (QELEMS + 255) / 256;
        pack_f16q_kernel<<<gpack, 256, 0, stream>>>(coeffs, QH);

        int geval = (n + 255) / 256;
        eval_f16q_kernel<<<geval, 256, 0, stream>>>(
            x, coeffs, (const ushort*)QH, out, n);
    } else {
        int block = 256;
        int grid = (n + block - 1) / block;
        spline_1pt_kernel<<<grid, block, 0, stream>>>(x, coeffs, out, n);
    }
}